// Round 10
// baseline (101.212 us; speedup 1.0000x reference)
//
#include <hip/hip_runtime.h>

// ExpertCompoundTracker: MoE load-EMA + pairwise co-activation histogram.
// Inputs: expert_indices [N,K] int32, expert_weights (UNUSED),
//         expert_load_ema [E] f32, expert_pair_coactivation [E,E] f32.
// Outputs concat: new_load_ema [64] then new_coact [4096], f32.
//
// R10 = R8 (full 4096-int slices — R9's triangle compaction regressed:
// index math cost > 0.6us traffic saving) but at 32 waves/CU: 512 blocks
// x 1024 threads (2 blocks/CU, full wave capacity), 4 tokens/thread.
// Theory: accum's residual ~8-10us is load/atomic latency exposure at 16
// waves/CU; doubling TLP halves it for +1.5us slice traffic.
// Keeps: batched loads + sched_barrier pin (R5), plain stores / no ws
// pre-zero / no global atomics (R7), no fences (R6), rowsum==3*count (R1).

#define N_TOKENS    2097152
#define NUM_EXPERTS 64
#define NCELLS      (NUM_EXPERTS * NUM_EXPERTS)  // 4096
#define NBLOCKS     512
#define NTHREADS    1024
#define STRIDE      (NBLOCKS * NTHREADS)         // 524288 threads -> 4 tokens each
#define SLICE       (NCELLS + NUM_EXPERTS)       // 4160 ints per slice (16B-aligned)

__device__ __forceinline__ void pair_add(int* s, int a, int b) {
    const int lo = min(a, b), hi = max(a, b);
    // bijective in-row swizzle: bank = (hi%32) ^ (lo&31) -> uniform
    atomicAdd(&s[(lo << 6) + (hi ^ (lo & 31))], 1);
}

__device__ __forceinline__ void token_add(int* s, int4 v) {
    pair_add(s, v.x, v.y);
    pair_add(s, v.x, v.z);
    pair_add(s, v.x, v.w);
    pair_add(s, v.y, v.z);
    pair_add(s, v.y, v.w);
    pair_add(s, v.z, v.w);
}

__global__ __launch_bounds__(NTHREADS) void coact_accum_kernel(
    const int* __restrict__ idx, int* __restrict__ ws)
{
    __shared__ int s_coact[NCELLS];   // 16 KB, swizzled upper-triangle cells
    __shared__ int s_row[NUM_EXPERTS];
    ((int4*)s_coact)[threadIdx.x] = make_int4(0, 0, 0, 0);
    if (threadIdx.x < NUM_EXPERTS) s_row[threadIdx.x] = 0;
    __syncthreads();

    const int tid = blockIdx.x * NTHREADS + threadIdx.x;
    const int4* __restrict__ idx4 = (const int4*)idx;

    // All 4 independent global_load_dwordx4 in flight, one vmcnt drain
    // (R3/R4: compiler re-serializes to save VGPRs if allowed).
    int4 v[4];
    #pragma unroll
    for (int i = 0; i < 4; ++i) v[i] = idx4[tid + i * STRIDE];
    __builtin_amdgcn_sched_barrier(0);

    #pragma unroll
    for (int i = 0; i < 4; ++i) token_add(s_coact, v[i]);

    __syncthreads();

    // Block-local rowsum_e = sum_{j>e} U[e][j] + 2*U[e][e] + sum_{j<e} U[j][e]
    // (== 3 * block-local count[e]; summed across slices in finalize).
    {
        const int e = threadIdx.x & 63;
        const int c = threadIdx.x >> 6;            // 16 chunks of 4 columns
        int p = 0;
        #pragma unroll
        for (int k = 0; k < 4; ++k) {
            const int j = c * 4 + k;
            int u;
            if (j >= e) {
                u = s_coact[(e << 6) + (j ^ (e & 31))];
                if (j == e) u <<= 1;               // diagonal counts twice
            } else {
                u = s_coact[(j << 6) + (e ^ (j & 31))];
            }
            p += u;
        }
        atomicAdd(&s_row[e], p);
    }
    __syncthreads();

    // Plain-store the slice: no pre-zero needed, no global atomics.
    int* slice = ws + blockIdx.x * SLICE;
    ((int4*)slice)[threadIdx.x] = ((const int4*)s_coact)[threadIdx.x];
    if (threadIdx.x < NUM_EXPERTS / 4) {
        ((int4*)(slice + NCELLS))[threadIdx.x] = ((const int4*)s_row)[threadIdx.x];
    }
}

__global__ __launch_bounds__(1024) void finalize_kernel(
    const int* __restrict__ ws,
    const float* __restrict__ ema_in,
    const float* __restrict__ coact_in,
    float* __restrict__ out)
{
    __shared__ int red[1024];
    __shared__ int rowf[NUM_EXPERTS];
    __shared__ int s_rowsum;
    const int b = blockIdx.x;       // expert / matrix row
    const int t = threadIdx.x;
    if (t == 0) s_rowsum = 0;

    // EMA partial: one slice-rowsum per thread for t < NBLOCKS.
    const int ema_part = (t < NBLOCKS) ? ws[t * SLICE + NCELLS + b] : 0;

    // Reduce swizzled row b over 512 slices: 16 lane-groups x 32 slices,
    // lane-consecutive -> coalesced 256B per read.
    const int g = t >> 6, lane = t & 63;
    int acc = 0;
    #pragma unroll 8
    for (int s = g * 32; s < g * 32 + 32; ++s)
        acc += ws[s * SLICE + b * 64 + lane];
    red[t] = acc;
    __syncthreads();                 // also orders s_rowsum init before atomics

    if (t < NUM_EXPERTS) {
        int v = 0;
        #pragma unroll
        for (int gg = 0; gg < 16; ++gg) v += red[gg * 64 + t];
        rowf[t] = v;                 // rowf[pos] = U[b][hi] at pos = hi^(b&31)
    }
    if (t < NBLOCKS) atomicAdd(&s_rowsum, ema_part);
    __syncthreads();

    // Write symmetric outputs: block b owns row b (j>=b) and column b (j>b).
    if (t < NUM_EXPERTS) {
        const int j = t;
        if (j > b) {
            const float d = (float)rowf[j ^ (b & 31)];
            out[NUM_EXPERTS + b * 64 + j] = coact_in[b * 64 + j] + d;
            out[NUM_EXPERTS + j * 64 + b] = coact_in[j * 64 + b] + d;
        } else if (j == b) {
            out[NUM_EXPERTS + b * 65] =
                coact_in[b * 65] + 2.0f * (float)rowf[b ^ (b & 31)];
        }
    }
    if (t == 0) {
        const int count = s_rowsum / 3;   // exact: rowsum == 3*count
        const float load = (float)count / (float)N_TOKENS;
        out[b] = ema_in[b] * 0.99f + load * 0.01f;
    }
}

extern "C" void kernel_launch(void* const* d_in, const int* in_sizes, int n_in,
                              void* d_out, int out_size, void* d_ws, size_t ws_size,
                              hipStream_t stream)
{
    const int*   idx      = (const int*)d_in[0];
    // d_in[1] = expert_weights: unused by the reference -> never read.
    const float* ema_in   = (const float*)d_in[2];
    const float* coact_in = (const float*)d_in[3];
    float*       out      = (float*)d_out;
    int*         ws       = (int*)d_ws;   // 512 slices x 4160 ints = 8.5 MB, write-before-read

    coact_accum_kernel<<<NBLOCKS, NTHREADS, 0, stream>>>(idx, ws);
    finalize_kernel<<<NUM_EXPERTS, 1024, 0, stream>>>(ws, ema_in, coact_in, out);
}

// Round 11
// 98.598 us; speedup vs baseline: 1.0265x; 1.0265x over previous
//
#include <hip/hip_runtime.h>

// ExpertCompoundTracker: MoE load-EMA + pairwise co-activation histogram.
// Inputs: expert_indices [N,K] int32, expert_weights (UNUSED),
//         expert_load_ema [E] f32, expert_pair_coactivation [E,E] f32.
// Outputs concat: new_load_ema [64] then new_coact [4096], f32.
//
// R11 = exact revert to R8, the measured optimum of the explored space:
//   R7 512x512/8tok/512sl = 102.7 | R8 256x1024/8tok/256sl = 99.0 (best)
//   R9 compacted slices    = 100.8 | R10 512x1024/4tok/512sl = 101.2
// Load-bearing structure (verified across rounds):
//  - 8 tokens/thread, ALL loads batched before use + sched_barrier(0) pin
//    (R3/R4: compiler otherwise re-serializes loads to save VGPRs).
//  - per-block LDS histogram, upper-triangle only (R2), XOR bank swizzle.
//  - plain-store private ws slices, write-before-read => no ws pre-zero,
//    no global atomics (R7/R8).
//  - NO per-block device fences / last-block fusion (R6: catastrophic on
//    non-coherent XCD L2s). Kernel boundary provides ordering for free.
//  - EMA via rowsum==3*count identity (R1), integer-exact => absmax 0.
// Remaining time is harness fixed traffic (~70us, HBM-bound) + 2 latency-
// bound dispatches; R9/R10 showed both remaining levers are negative.

#define N_TOKENS    2097152
#define NUM_EXPERTS 64
#define NCELLS      (NUM_EXPERTS * NUM_EXPERTS)  // 4096
#define NBLOCKS     256
#define NTHREADS    1024
#define STRIDE      (NBLOCKS * NTHREADS)         // 262144 threads -> 8 tokens each
#define SLICE       (NCELLS + NUM_EXPERTS)       // 4160 ints per slice (16B-aligned)

__device__ __forceinline__ void pair_add(int* s, int a, int b) {
    const int lo = min(a, b), hi = max(a, b);
    // bijective in-row swizzle: bank = (hi%32) ^ (lo&31) -> uniform
    atomicAdd(&s[(lo << 6) + (hi ^ (lo & 31))], 1);
}

__device__ __forceinline__ void token_add(int* s, int4 v) {
    pair_add(s, v.x, v.y);
    pair_add(s, v.x, v.z);
    pair_add(s, v.x, v.w);
    pair_add(s, v.y, v.z);
    pair_add(s, v.y, v.w);
    pair_add(s, v.z, v.w);
}

__global__ __launch_bounds__(NTHREADS) void coact_accum_kernel(
    const int* __restrict__ idx, int* __restrict__ ws)
{
    __shared__ int s_coact[NCELLS];   // 16 KB, swizzled upper-triangle cells
    __shared__ int s_row[NUM_EXPERTS];
    ((int4*)s_coact)[threadIdx.x] = make_int4(0, 0, 0, 0);
    if (threadIdx.x < NUM_EXPERTS) s_row[threadIdx.x] = 0;
    __syncthreads();

    const int tid = blockIdx.x * NTHREADS + threadIdx.x;
    const int4* __restrict__ idx4 = (const int4*)idx;

    // All 8 independent global_load_dwordx4 in flight (4 KB/wave), then one
    // vmcnt drain (R3/R4: compiler re-serializes to save VGPRs if allowed).
    int4 v[8];
    #pragma unroll
    for (int i = 0; i < 8; ++i) v[i] = idx4[tid + i * STRIDE];
    __builtin_amdgcn_sched_barrier(0);

    #pragma unroll
    for (int i = 0; i < 8; ++i) token_add(s_coact, v[i]);

    __syncthreads();

    // Block-local rowsum_e = sum_{j>e} U[e][j] + 2*U[e][e] + sum_{j<e} U[j][e]
    // (== 3 * block-local count[e]; summed across slices in finalize).
    {
        const int e = threadIdx.x & 63;
        const int c = threadIdx.x >> 6;            // 16 chunks of 4 columns
        int p = 0;
        #pragma unroll
        for (int k = 0; k < 4; ++k) {
            const int j = c * 4 + k;
            int u;
            if (j >= e) {
                u = s_coact[(e << 6) + (j ^ (e & 31))];
                if (j == e) u <<= 1;               // diagonal counts twice
            } else {
                u = s_coact[(j << 6) + (e ^ (j & 31))];
            }
            p += u;
        }
        atomicAdd(&s_row[e], p);
    }
    __syncthreads();

    // Plain-store the slice: no pre-zero needed, no global atomics.
    int* slice = ws + blockIdx.x * SLICE;
    ((int4*)slice)[threadIdx.x] = ((const int4*)s_coact)[threadIdx.x];
    if (threadIdx.x < NUM_EXPERTS / 4) {
        ((int4*)(slice + NCELLS))[threadIdx.x] = ((const int4*)s_row)[threadIdx.x];
    }
}

__global__ __launch_bounds__(512) void finalize_kernel(
    const int* __restrict__ ws,
    const float* __restrict__ ema_in,
    const float* __restrict__ coact_in,
    float* __restrict__ out)
{
    __shared__ int red[512];
    __shared__ int rowf[NUM_EXPERTS];
    __shared__ int s_rowsum;
    const int b = blockIdx.x;       // expert / matrix row
    const int t = threadIdx.x;
    if (t == 0) s_rowsum = 0;

    // EMA partial: one slice-rowsum per thread for t < NBLOCKS.
    const int ema_part = (t < NBLOCKS) ? ws[t * SLICE + NCELLS + b] : 0;

    // Reduce swizzled row b over 256 slices: lane-consecutive -> coalesced.
    const int g = t >> 6, lane = t & 63;           // 8 lane-groups x 32 slices
    int acc = 0;
    #pragma unroll 8
    for (int s = g * 32; s < g * 32 + 32; ++s)
        acc += ws[s * SLICE + b * 64 + lane];
    red[t] = acc;
    __syncthreads();                 // also orders s_rowsum init before atomics

    if (t < NUM_EXPERTS) {
        int v = 0;
        #pragma unroll
        for (int gg = 0; gg < 8; ++gg) v += red[gg * 64 + t];
        rowf[t] = v;                 // rowf[pos] = U[b][hi] at pos = hi^(b&31)
    }
    if (t < NBLOCKS) atomicAdd(&s_rowsum, ema_part);
    __syncthreads();

    // Write symmetric outputs: block b owns row b (j>=b) and column b (j>b).
    if (t < NUM_EXPERTS) {
        const int j = t;
        if (j > b) {
            const float d = (float)rowf[j ^ (b & 31)];
            out[NUM_EXPERTS + b * 64 + j] = coact_in[b * 64 + j] + d;
            out[NUM_EXPERTS + j * 64 + b] = coact_in[j * 64 + b] + d;
        } else if (j == b) {
            out[NUM_EXPERTS + b * 65] =
                coact_in[b * 65] + 2.0f * (float)rowf[b ^ (b & 31)];
        }
    }
    if (t == 0) {
        const int count = s_rowsum / 3;   // exact: rowsum == 3*count
        const float load = (float)count / (float)N_TOKENS;
        out[b] = ema_in[b] * 0.99f + load * 0.01f;
    }
}

extern "C" void kernel_launch(void* const* d_in, const int* in_sizes, int n_in,
                              void* d_out, int out_size, void* d_ws, size_t ws_size,
                              hipStream_t stream)
{
    const int*   idx      = (const int*)d_in[0];
    // d_in[1] = expert_weights: unused by the reference -> never read.
    const float* ema_in   = (const float*)d_in[2];
    const float* coact_in = (const float*)d_in[3];
    float*       out      = (float*)d_out;
    int*         ws       = (int*)d_ws;   // 256 slices x 4160 ints = 4.25 MB, write-before-read

    coact_accum_kernel<<<NBLOCKS, NTHREADS, 0, stream>>>(idx, ws);
    finalize_kernel<<<NUM_EXPERTS, 512, 0, stream>>>(ws, ema_in, coact_in, out);
}